// Round 1
// baseline (832.303 us; speedup 1.0000x reference)
//
#include <hip/hip_runtime.h>

// ADI diffusion: B=16, C=8, S=128, 10 steps.
// u viewed as [B][C][S][S] fp32, worked in-place in d_out.
// Sequence (21 launches):
//   rows<MIX,POST>(t=0)                      : mix + x-half-solve
//   repeat k=0..9:
//     cols(t=k*dt+dt/2)                      : y full solve
//     k<9 : rows<PRE,MIX,POST>(t=(k+1)*dt)   : x-half + mix + x-half (same t!)
//     k==9: rows<PRE>(t=10*dt)               : final x-half

constexpr int S_ = 128;
constexpr int C_ = 8;
constexpr int HT = 8;            // h-rows per block in rows kernel
constexpr float EPSF = 1e-6f;

__device__ __forceinline__ void thomas_row(float* __restrict__ urow,
                                           float* __restrict__ crow) {
    // urow[i]: rhs in, solution out. crow[i]: coeff in, clobbered with c_star.
    float cs = 0.f, ds = 0.f;
    for (int i = 0; i < S_; ++i) {
        float co = crow[i];
        float bb = (i == 0 || i == S_ - 1) ? (1.f + co) : fmaf(2.f, co, 1.f);
        float denom = fmaf(co, cs, bb) + EPSF;     // b - a*cs + eps, a=-co
        float rd = __builtin_amdgcn_rcpf(denom);
        ds = fmaf(co, ds, urow[i]) * rd;           // (d - a*ds)/denom
        cs = (-co) * rd;                           // c/denom, c=-co
        crow[i] = cs;
        urow[i] = ds;
    }
    float x = urow[S_ - 1];
    for (int i = S_ - 2; i >= 0; --i) {
        x = fmaf(-crow[i], x, urow[i]);
        urow[i] = x;
    }
}

template <bool PRE, bool MIX, bool POST>
__global__ __launch_bounds__(64) void rows_kernel(
    const float* usrc, float* udst,
    const float* __restrict__ ab, const float* __restrict__ atc,
    const float* __restrict__ cm, float t) {
    __shared__ float su[64][S_ + 1];   // row r = c*HT + hh, stride 129 -> bank (r+i)%32
    __shared__ float sc[64][S_ + 1];
    __shared__ float sM[C_ * C_];

    const int tid = threadIdx.x;
    const int b = blockIdx.x >> 4;
    const int h0 = (blockIdx.x & 15) * HT;

    // stage u tile (coalesced: consecutive tid -> consecutive w)
    for (int idx = tid; idx < 64 * S_; idx += 64) {
        int r = idx >> 7, w = idx & 127;
        int c = r >> 3, hh = r & 7;
        su[r][w] = usrc[(((b * C_ + c) * S_) + h0 + hh) * S_ + w];
    }
    if (PRE || POST) {
        for (int idx = tid; idx < 64 * S_; idx += 64) {
            int r = idx >> 7, w = idx & 127;
            int c = r >> 3, hh = r & 7;
            int g = ((c * S_) + h0 + hh) * S_ + w;
            float al = fmaf(atc[g], t, ab[g]);
            al = fminf(fmaxf(al, EPSF), 10.f);
            sc[r][w] = al * 0.0005f;               // * (dt/2)/dx^2
        }
    }
    if (MIX) sM[tid] = cm[tid];
    __syncthreads();

    if (PRE) thomas_row(&su[tid][0], &sc[tid][0]);

    if (MIX) {
        __syncthreads();
        for (int p = tid; p < HT * S_; p += 64) {
            int hh = p >> 7, w = p & 127;
            float vin[C_], vout[C_];
            #pragma unroll
            for (int c = 0; c < C_; ++c) vin[c] = su[c * HT + hh][w];
            #pragma unroll
            for (int d = 0; d < C_; ++d) {
                float acc = 0.f;
                #pragma unroll
                for (int c = 0; c < C_; ++c) acc = fmaf(sM[d * C_ + c], vin[c], acc);
                vout[d] = acc;
            }
            #pragma unroll
            for (int d = 0; d < C_; ++d) su[d * HT + hh][w] = vout[d];
        }
    }

    if (POST) {
        if (PRE) {  // sc clobbered by PRE's c_star -> reload (same t)
            __syncthreads();
            for (int idx = tid; idx < 64 * S_; idx += 64) {
                int r = idx >> 7, w = idx & 127;
                int c = r >> 3, hh = r & 7;
                int g = ((c * S_) + h0 + hh) * S_ + w;
                float al = fmaf(atc[g], t, ab[g]);
                al = fminf(fmaxf(al, EPSF), 10.f);
                sc[r][w] = al * 0.0005f;
            }
        }
        __syncthreads();
        thomas_row(&su[tid][0], &sc[tid][0]);
    }

    __syncthreads();
    for (int idx = tid; idx < 64 * S_; idx += 64) {
        int r = idx >> 7, w = idx & 127;
        int c = r >> 3, hh = r & 7;
        udst[(((b * C_ + c) * S_) + h0 + hh) * S_ + w] = su[r][w];
    }
}

__global__ __launch_bounds__(64) void cols_kernel(
    float* u, const float* __restrict__ bb, const float* __restrict__ btc,
    float t) {
    __shared__ float su[S_][65];   // [h][w_local], stride 65 -> bank (h+w)%32
    __shared__ float sc[S_][65];

    const int tid = threadIdx.x;
    const int bc = blockIdx.x >> 1;        // b*C + c
    const int c = bc & 7;
    const int w0 = (blockIdx.x & 1) * 64;
    const size_t base = (size_t)bc * S_ * S_ + w0;

    for (int idx = tid; idx < S_ * 64; idx += 64) {
        int h = idx >> 6, wl = idx & 63;
        su[h][wl] = u[base + h * S_ + wl];
        int g = (c * S_ + h) * S_ + w0 + wl;
        float be = fmaf(btc[g], t, bb[g]);
        be = fminf(fmaxf(be, EPSF), 10.f);
        sc[h][wl] = be * 0.001f;           // * dt/dy^2
    }
    __syncthreads();

    // thread tid solves column tid (strided LDS view, conflict-free)
    {
        float cs = 0.f, ds = 0.f;
        for (int i = 0; i < S_; ++i) {
            float co = sc[i][tid];
            float b2 = (i == 0 || i == S_ - 1) ? (1.f + co) : fmaf(2.f, co, 1.f);
            float denom = fmaf(co, cs, b2) + EPSF;
            float rd = __builtin_amdgcn_rcpf(denom);
            ds = fmaf(co, ds, su[i][tid]) * rd;
            cs = (-co) * rd;
            sc[i][tid] = cs;
            su[i][tid] = ds;
        }
        float x = su[S_ - 1][tid];
        for (int i = S_ - 2; i >= 0; --i) {
            x = fmaf(-sc[i][tid], x, su[i][tid]);
            su[i][tid] = x;
        }
    }
    __syncthreads();

    for (int idx = tid; idx < S_ * 64; idx += 64) {
        int h = idx >> 6, wl = idx & 63;
        u[base + h * S_ + wl] = su[h][wl];
    }
}

extern "C" void kernel_launch(void* const* d_in, const int* in_sizes, int n_in,
                              void* d_out, int out_size, void* d_ws, size_t ws_size,
                              hipStream_t stream) {
    const float* u_in = (const float*)d_in[0];
    const float* ab   = (const float*)d_in[1];
    const float* bbta = (const float*)d_in[2];
    const float* atc  = (const float*)d_in[3];
    const float* btc  = (const float*)d_in[4];
    const float* cm   = (const float*)d_in[5];
    float* u = (float*)d_out;

    const dim3 grid(256), blk(64);
    double t = 0.0;
    const double half = 0.0005;

    // step 0 head: mix + x half-step at t=0 (reads pristine input)
    rows_kernel<false, true, true><<<grid, blk, 0, stream>>>(u_in, u, ab, atc, cm, (float)t);

    for (int k = 0; k < 10; ++k) {
        t += half;
        cols_kernel<<<grid, blk, 0, stream>>>(u, bbta, btc, (float)t);
        t += half;
        if (k < 9) {
            // trailing x of step k + mix + leading x of step k+1 (same t)
            rows_kernel<true, true, true><<<grid, blk, 0, stream>>>(u, u, ab, atc, cm, (float)t);
        } else {
            rows_kernel<true, false, false><<<grid, blk, 0, stream>>>(u, u, ab, atc, cm, (float)t);
        }
    }
}

// Round 2
// 708.474 us; speedup vs baseline: 1.1748x; 1.1748x over previous
//
#include <hip/hip_runtime.h>

// ADI diffusion B=16, C=8, S=128, 10 steps, in-place in d_out.
// Key restructure vs round 1:
//  - Tridiag matrix is batch-independent: factor once per (c,h,t) / (c,w,t),
//    apply to all 16 batches. Fused x|mix|x shares t -> factor once, apply 2x.
//  - All serial loops read from read-only LDS arrays and write to distinct
//    write-only ones, so the compiler can prefetch ds_reads off the chain.

constexpr int S_ = 128;
constexpr float EPSF = 1e-6f;

// ---------------------------------------------------------------------------
// x-sweep. grid = 128 h * 2 b-groups = 256 blocks, 64 threads.
// Block: fixed h, all c (8), batches b0..b0+7.
// Apply thread tid -> row r=tid: c = r>>3, bl = r&7 (b = b0+bl).
// ---------------------------------------------------------------------------
template <bool PRE, bool MIX, bool POST>
__global__ __launch_bounds__(64) void xsweep_kernel(
    const float* __restrict__ usrc, float* __restrict__ udst,
    const float* __restrict__ ab, const float* __restrict__ atc,
    const float* __restrict__ cm, float t)
{
    __shared__ float su [64][S_ + 1];   // data rows; bank (r+i)%32 -> 2 lanes/bank
    __shared__ float sds[64][S_ + 1];   // forward-sweep output (d_star)
    __shared__ float sco[8][S_ + 1];    // coeff per c
    __shared__ float srd[8][S_ + 1];    // 1/denom per c
    __shared__ float scs[8][S_ + 1];    // c_star per c
    __shared__ float sM[64];

    const int tid = threadIdx.x;
    const int h  = blockIdx.x >> 1;
    const int b0 = (blockIdx.x & 1) * 8;

    // stage u tile: row r = c*8+bl
    for (int p = tid; p < 64 * S_; p += 64) {
        const int r = p >> 7, i = p & 127;
        const int c = r >> 3, bl = r & 7;
        su[r][i] = usrc[(((size_t)(b0 + bl) * 8 + c) * S_ + h) * S_ + i];
    }
    // stage coeff (per c, shared over batch)
    for (int p = tid; p < 8 * S_; p += 64) {
        const int c = p >> 7, i = p & 127;
        const int g = (c * S_ + h) * S_ + i;
        float al = fmaf(atc[g], t, ab[g]);
        al = fminf(fmaxf(al, EPSF), 10.f);
        sco[c][i] = al * 0.0005f;          // * (dt/2)/dx^2
    }
    if (MIX) sM[tid] = cm[tid];
    __syncthreads();

    // factorize 8 rows (lanes 0..7): reads sco, writes srd/scs (disjoint)
    if (tid < 8) {
        float cs = 0.f;
        #pragma unroll 4
        for (int i = 0; i < S_; ++i) {
            const float co = sco[tid][i];
            const float bb = (i == 0 || i == S_ - 1) ? (1.f + co) : fmaf(2.f, co, 1.f);
            const float denom = fmaf(co, cs, bb) + EPSF;   // b - a*cs + eps, a=-co
            const float rd = __builtin_amdgcn_rcpf(denom);
            cs = -co * rd;                                 // c_star = c/denom, c=-co
            srd[tid][i] = rd;
            scs[tid][i] = cs;
        }
    }
    __syncthreads();

    const int r = tid;
    const int c = tid >> 3;

    if (PRE) {
        // forward: reads su/sco/srd, writes sds
        float ds = 0.f;
        #pragma unroll 8
        for (int i = 0; i < S_; ++i) {
            ds = fmaf(sco[c][i], ds, su[r][i]) * srd[c][i];
            sds[r][i] = ds;
        }
        __syncthreads();
        // backward: reads sds/scs, writes su
        float x = ds;
        su[r][S_ - 1] = x;
        #pragma unroll 8
        for (int i = S_ - 2; i >= 0; --i) {
            x = fmaf(-scs[c][i], x, sds[r][i]);
            su[r][i] = x;
        }
    }

    if (MIX) {
        __syncthreads();
        for (int p = tid; p < 8 * S_; p += 64) {
            const int bl = p >> 7, w = p & 127;
            float v[8], o[8];
            #pragma unroll
            for (int cc = 0; cc < 8; ++cc) v[cc] = su[cc * 8 + bl][w];
            #pragma unroll
            for (int d = 0; d < 8; ++d) {
                float acc = 0.f;
                #pragma unroll
                for (int cc = 0; cc < 8; ++cc) acc = fmaf(sM[d * 8 + cc], v[cc], acc);
                o[d] = acc;
            }
            #pragma unroll
            for (int d = 0; d < 8; ++d) su[d * 8 + bl][w] = o[d];
        }
    }

    if (POST) {
        __syncthreads();
        float ds = 0.f;
        #pragma unroll 8
        for (int i = 0; i < S_; ++i) {
            ds = fmaf(sco[c][i], ds, su[r][i]) * srd[c][i];
            sds[r][i] = ds;
        }
        __syncthreads();
        float x = ds;
        su[r][S_ - 1] = x;
        #pragma unroll 8
        for (int i = S_ - 2; i >= 0; --i) {
            x = fmaf(-scs[c][i], x, sds[r][i]);
            su[r][i] = x;
        }
    }

    __syncthreads();
    for (int p = tid; p < 64 * S_; p += 64) {
        const int rr = p >> 7, i = p & 127;
        const int cc = rr >> 3, bl = rr & 7;
        udst[(((size_t)(b0 + bl) * 8 + cc) * S_ + h) * S_ + i] = su[rr][i];
    }
}

// ---------------------------------------------------------------------------
// y-sweep. grid = 8 c * 32 w-tiles = 256 blocks, 64 threads.
// Block: fixed c, w0..w0+3, all 16 batches. Apply thread tid: wl=tid>>4, b=tid&15.
// ---------------------------------------------------------------------------
__global__ __launch_bounds__(64) void ysweep_kernel(
    float* __restrict__ u,
    const float* __restrict__ bb, const float* __restrict__ btc, float t)
{
    __shared__ float su [64][S_ + 1];   // row = wl*16+b, index = h
    __shared__ float sds[64][S_ + 1];
    __shared__ float sco[4][S_ + 1];
    __shared__ float srd[4][S_ + 1];
    __shared__ float scs[4][S_ + 1];

    const int tid = threadIdx.x;
    const int c  = blockIdx.x >> 5;
    const int w0 = (blockIdx.x & 31) * 4;

    // stage u: p -> wl = p&3, b = (p>>2)&15, h = p>>6
    for (int p = tid; p < 64 * S_; p += 64) {
        const int wl = p & 3, b = (p >> 2) & 15, hh = p >> 6;
        su[wl * 16 + b][hh] = u[(((size_t)b * 8 + c) * S_ + hh) * S_ + w0 + wl];
    }
    // stage coeff: p -> wl = p&3, h = p>>2
    for (int p = tid; p < 4 * S_; p += 64) {
        const int wl = p & 3, hh = p >> 2;
        const int g = (c * S_ + hh) * S_ + w0 + wl;
        float be = fmaf(btc[g], t, bb[g]);
        be = fminf(fmaxf(be, EPSF), 10.f);
        sco[wl][hh] = be * 0.001f;         // * dt/dy^2
    }
    __syncthreads();

    if (tid < 4) {
        float cs = 0.f;
        #pragma unroll 4
        for (int i = 0; i < S_; ++i) {
            const float co = sco[tid][i];
            const float b2 = (i == 0 || i == S_ - 1) ? (1.f + co) : fmaf(2.f, co, 1.f);
            const float denom = fmaf(co, cs, b2) + EPSF;
            const float rd = __builtin_amdgcn_rcpf(denom);
            cs = -co * rd;
            srd[tid][i] = rd;
            scs[tid][i] = cs;
        }
    }
    __syncthreads();

    const int r = tid;
    const int wl = tid >> 4;

    {
        float ds = 0.f;
        #pragma unroll 8
        for (int i = 0; i < S_; ++i) {
            ds = fmaf(sco[wl][i], ds, su[r][i]) * srd[wl][i];
            sds[r][i] = ds;
        }
        __syncthreads();
        float x = ds;
        su[r][S_ - 1] = x;
        #pragma unroll 8
        for (int i = S_ - 2; i >= 0; --i) {
            x = fmaf(-scs[wl][i], x, sds[r][i]);
            su[r][i] = x;
        }
    }
    __syncthreads();

    for (int p = tid; p < 64 * S_; p += 64) {
        const int wll = p & 3, b = (p >> 2) & 15, hh = p >> 6;
        u[(((size_t)b * 8 + c) * S_ + hh) * S_ + w0 + wll] = su[wll * 16 + b][hh];
    }
}

extern "C" void kernel_launch(void* const* d_in, const int* in_sizes, int n_in,
                              void* d_out, int out_size, void* d_ws, size_t ws_size,
                              hipStream_t stream) {
    const float* u_in = (const float*)d_in[0];
    const float* ab   = (const float*)d_in[1];
    const float* bbta = (const float*)d_in[2];
    const float* atc  = (const float*)d_in[3];
    const float* btc  = (const float*)d_in[4];
    const float* cm   = (const float*)d_in[5];
    float* u = (float*)d_out;

    const dim3 grid(256), blk(64);
    double t = 0.0;
    const double half = 0.0005;

    // step-0 head: mix + x half (t=0), reads pristine input
    xsweep_kernel<false, true, true><<<grid, blk, 0, stream>>>(u_in, u, ab, atc, cm, (float)t);

    for (int k = 0; k < 10; ++k) {
        t += half;
        ysweep_kernel<<<grid, blk, 0, stream>>>(u, bbta, btc, (float)t);
        t += half;
        if (k < 9) {
            // trailing x of step k + mix + leading x of step k+1 (same t, same factorization)
            xsweep_kernel<true, true, true><<<grid, blk, 0, stream>>>(u, u, ab, atc, cm, (float)t);
        } else {
            xsweep_kernel<true, false, false><<<grid, blk, 0, stream>>>(u, u, ab, atc, cm, (float)t);
        }
    }
}

// Round 3
// 532.436 us; speedup vs baseline: 1.5632x; 1.3306x over previous
//
#include <hip/hip_runtime.h>

// ADI diffusion B=16, C=8, S=128, 10 steps, in-place in d_out.
// Round-3 structure:
//  - xsweep: 128 blocks (one per h), 128 threads (row = b*8+c). Full slab in
//    LDS, factorization shared across the 16 batches per c and reused for the
//    fused x|mix|x pair (same t). All serial loops read from read-only LDS
//    arrays and write to distinct ones (no alias -> prefetchable).
//  - ysweep: 256 blocks (bc, w-half), 64 threads (one column each). No
//    staging: u/beta reads and u writes are lane-contiguous in w (coalesced),
//    rhs/coeff loads are chain-independent (software-pipelined). c*/d* go to
//    padded LDS. Zero barriers.

constexpr int S_ = 128;
constexpr float EPSF = 1e-6f;

// ---------------------------------------------------------------------------
template <bool PRE, bool MIX, bool POST>
__global__ __launch_bounds__(128) void xsweep_kernel(
    const float* __restrict__ usrc, float* __restrict__ udst,
    const float* __restrict__ ab, const float* __restrict__ atc,
    const float* __restrict__ cm, float t)
{
    __shared__ float su [128][S_ + 1];  // row r = b*8+c ; bank (r+i)%32
    __shared__ float sds[128][S_ + 1];  // d_star scratch
    __shared__ float sco[8][S_ + 1];    // coeff per c (batch-shared)
    __shared__ float srd[8][S_ + 1];    // 1/denom per c
    __shared__ float scs[8][S_ + 1];    // c_star per c
    __shared__ float sM[64];

    const int tid = threadIdx.x;
    const int h = blockIdx.x;

    // stage u slab: 128 rows x 128, lanes contiguous in i (coalesced)
    for (int p = tid; p < 128 * S_; p += 128) {
        const int r = p >> 7, i = p & 127;
        su[r][i] = usrc[((size_t)r * S_ + h) * S_ + i];
    }
    // stage coeff (per c, shared over batch), coalesced
    for (int p = tid; p < 8 * S_; p += 128) {
        const int c = p >> 7, i = p & 127;
        const int g = (c * S_ + h) * S_ + i;
        float al = fmaf(atc[g], t, ab[g]);
        al = fminf(fmaxf(al, EPSF), 10.f);
        sco[c][i] = al * 0.0005f;          // * (dt/2)/dx^2
    }
    if (MIX && tid < 64) sM[tid] = cm[tid];
    __syncthreads();

    // factorize once per c (8 lanes): reads sco, writes srd/scs (disjoint)
    if (tid < 8) {
        float cs = 0.f;
        #pragma unroll 4
        for (int i = 0; i < S_; ++i) {
            const float co = sco[tid][i];
            const float bb = (i == 0 || i == S_ - 1) ? (1.f + co) : fmaf(2.f, co, 1.f);
            const float denom = fmaf(co, cs, bb) + EPSF;   // b - a*cs + eps
            const float rd = __builtin_amdgcn_rcpf(denom);
            cs = -co * rd;                                 // c_star
            srd[tid][i] = rd;
            scs[tid][i] = cs;
        }
    }
    __syncthreads();

    const int r = tid;
    const int c = tid & 7;

    if (PRE) {
        float ds = 0.f;
        #pragma unroll 8
        for (int i = 0; i < S_; ++i) {
            ds = fmaf(sco[c][i], ds, su[r][i]) * srd[c][i];
            sds[r][i] = ds;
        }
        // backward (row private to this thread: no barrier needed)
        float x = ds;
        su[r][S_ - 1] = x;
        #pragma unroll 8
        for (int i = S_ - 2; i >= 0; --i) {
            x = fmaf(-scs[c][i], x, sds[r][i]);
            su[r][i] = x;
        }
    }

    if (MIX) {
        __syncthreads();
        for (int p = tid; p < 16 * S_; p += 128) {   // (b, w) pairs
            const int b = p >> 7, w = p & 127;
            float v[8], o[8];
            #pragma unroll
            for (int cc = 0; cc < 8; ++cc) v[cc] = su[b * 8 + cc][w];
            #pragma unroll
            for (int d = 0; d < 8; ++d) {
                float acc = 0.f;
                #pragma unroll
                for (int cc = 0; cc < 8; ++cc) acc = fmaf(sM[d * 8 + cc], v[cc], acc);
                o[d] = acc;
            }
            #pragma unroll
            for (int d = 0; d < 8; ++d) su[b * 8 + d][w] = o[d];
        }
    }

    if (POST) {
        __syncthreads();
        float ds = 0.f;
        #pragma unroll 8
        for (int i = 0; i < S_; ++i) {
            ds = fmaf(sco[c][i], ds, su[r][i]) * srd[c][i];
            sds[r][i] = ds;
        }
        float x = ds;
        su[r][S_ - 1] = x;
        #pragma unroll 8
        for (int i = S_ - 2; i >= 0; --i) {
            x = fmaf(-scs[c][i], x, sds[r][i]);
            su[r][i] = x;
        }
    }

    __syncthreads();
    for (int p = tid; p < 128 * S_; p += 128) {
        const int r2 = p >> 7, i = p & 127;
        udst[((size_t)r2 * S_ + h) * S_ + i] = su[r2][i];
    }
}

// ---------------------------------------------------------------------------
// ysweep: 256 blocks = (bc, w-half), 64 threads, one column per thread.
// ---------------------------------------------------------------------------
__global__ __launch_bounds__(64) void ysweep_kernel(
    float* __restrict__ u,
    const float* __restrict__ bbeta, const float* __restrict__ btc, float t)
{
    __shared__ float scs[S_][65];   // bank (i+tid)%32, conflict-free
    __shared__ float sds[S_][65];

    const int tid = threadIdx.x;
    const int bc = blockIdx.x >> 1;
    const int c  = bc & 7;
    const int w  = ((blockIdx.x & 1) << 6) + tid;

    float* __restrict__ ucol = u + (size_t)bc * S_ * S_ + w;
    const float* __restrict__ bbp = bbeta + (size_t)c * S_ * S_ + w;
    const float* __restrict__ btp = btc   + (size_t)c * S_ * S_ + w;

    float cs = 0.f, ds = 0.f;
    #pragma unroll 8
    for (int i = 0; i < S_; ++i) {
        float be = fmaf(btp[i * S_], t, bbp[i * S_]);
        be = fminf(fmaxf(be, EPSF), 10.f);
        const float co = be * 0.001f;                         // * dt/dy^2
        const float b2 = (i == 0 || i == S_ - 1) ? (1.f + co) : fmaf(2.f, co, 1.f);
        const float denom = fmaf(co, cs, b2) + EPSF;
        const float rd = __builtin_amdgcn_rcpf(denom);
        ds = fmaf(co, ds, ucol[i * S_]) * rd;
        cs = -co * rd;
        scs[i][tid] = cs;
        sds[i][tid] = ds;
    }
    // backward: column private to this thread, no barrier
    float x = ds;
    ucol[(S_ - 1) * S_] = x;
    #pragma unroll 8
    for (int i = S_ - 2; i >= 0; --i) {
        x = fmaf(-scs[i][tid], x, sds[i][tid]);
        ucol[i * S_] = x;
    }
}

extern "C" void kernel_launch(void* const* d_in, const int* in_sizes, int n_in,
                              void* d_out, int out_size, void* d_ws, size_t ws_size,
                              hipStream_t stream) {
    const float* u_in = (const float*)d_in[0];
    const float* ab   = (const float*)d_in[1];
    const float* bbta = (const float*)d_in[2];
    const float* atc  = (const float*)d_in[3];
    const float* btc  = (const float*)d_in[4];
    const float* cm   = (const float*)d_in[5];
    float* u = (float*)d_out;

    const dim3 xgrid(128), xblk(128);
    const dim3 ygrid(256), yblk(64);
    double t = 0.0;
    const double half = 0.0005;

    // step-0 head: mix + x half (t=0), reads pristine input, fills all of d_out
    xsweep_kernel<false, true, true><<<xgrid, xblk, 0, stream>>>(u_in, u, ab, atc, cm, (float)t);

    for (int k = 0; k < 10; ++k) {
        t += half;
        ysweep_kernel<<<ygrid, yblk, 0, stream>>>(u, bbta, btc, (float)t);
        t += half;
        if (k < 9) {
            // trailing x of step k + mix + leading x of step k+1 (same t,
            // same factorization)
            xsweep_kernel<true, true, true><<<xgrid, xblk, 0, stream>>>(u, u, ab, atc, cm, (float)t);
        } else {
            xsweep_kernel<true, false, false><<<xgrid, xblk, 0, stream>>>(u, u, ab, atc, cm, (float)t);
        }
    }
}

// Round 4
// 265.562 us; speedup vs baseline: 3.1341x; 2.0049x over previous
//
#include <hip/hip_runtime.h>

// ADI diffusion B=16, C=8, S=128, 10 steps, in-place in d_out.
// Round 4: the tridiagonal systems are near-identity (off-diag co <= 0.005
// even at the alpha/beta clip ceiling), so replace the serial Thomas solve
// with Jacobi iteration: x0 = D^-1 d; x^{k+1} = D^-1(d + co*(x_left+x_right)).
// Contraction <= 0.01 per iter -> 3 iters give ~1e-8 error (actual data:
// ~1e-12), vs 0.127 threshold. This makes every phase an embarrassingly
// parallel 3-point stencil: 512 blocks x 256 threads, coeff/rhs in registers,
// only the iterate in LDS (16 KB), all accesses lane-consecutive.

constexpr int S_ = 128;
constexpr float EPSF = 1e-6f;
constexpr int NIT = 3;

// ---------------------------------------------------------------------------
// x-phase solve along w. Thread owns 16 elements p = tid + 256k of a
// (b, h0..h0+3) tile: p = c*512 + hh*128 + w.
// ---------------------------------------------------------------------------
__device__ __forceinline__ void jsolve_x(float* __restrict__ sU, int tid,
                                         const float (&co)[16],
                                         const float (&rb)[16],
                                         float (&d)[16]) {
    float x[16];
    #pragma unroll
    for (int k = 0; k < 16; ++k) { x[k] = rb[k] * d[k]; sU[tid + 256 * k] = x[k]; }
    __syncthreads();
    for (int it = 0; it < NIT; ++it) {
        #pragma unroll
        for (int k = 0; k < 16; ++k) {
            const int p = tid + 256 * k;
            const int w = p & 127;
            const float xl = (w > 0)   ? sU[p - 1] : 0.f;
            const float xr = (w < 127) ? sU[p + 1] : 0.f;
            x[k] = rb[k] * fmaf(co[k], xl + xr, d[k]);
        }
        __syncthreads();
        #pragma unroll
        for (int k = 0; k < 16; ++k) sU[tid + 256 * k] = x[k];
        __syncthreads();
    }
    #pragma unroll
    for (int k = 0; k < 16; ++k) d[k] = x[k];
}

template <bool PRE, bool MIX, bool POST>
__global__ __launch_bounds__(256) void xmix_kernel(
    const float* __restrict__ usrc, float* __restrict__ udst,
    const float* __restrict__ ab, const float* __restrict__ atc,
    const float* __restrict__ cm, float t)
{
    __shared__ float sU[8 * 4 * 128];   // 16 KB
    __shared__ float sM[64];

    const int tid = threadIdx.x;
    const int b  = blockIdx.x >> 5;
    const int h0 = (blockIdx.x & 31) << 2;

    if (MIX && tid < 64) sM[tid] = cm[tid];

    float d[16], co[16], rb[16];
    #pragma unroll
    for (int k = 0; k < 16; ++k) {
        const int p = tid + 256 * k;
        const int w = p & 127, hh = (p >> 7) & 3, c = p >> 9;
        const size_t gi = ((size_t)(b * 8 + c) * S_ + (h0 + hh)) * S_ + w;
        const int    ga = ((c * S_) + (h0 + hh)) * S_ + w;
        d[k] = usrc[gi];
        float al = fmaf(atc[ga], t, ab[ga]);
        al = fminf(fmaxf(al, EPSF), 10.f);
        const float cc = al * 0.0005f;          // * (dt/2)/dx^2
        co[k] = cc;
        const float nb = (w == 0 || w == 127) ? 1.f : 2.f;
        rb[k] = __builtin_amdgcn_rcpf(fmaf(nb, cc, 1.f) + EPSF);
    }

    if (PRE) jsolve_x(sU, tid, co, rb, d);      // leaves solution in d and sU

    if (MIX) {
        if (!PRE) {   // sU must hold the mix input
            #pragma unroll
            for (int k = 0; k < 16; ++k) sU[tid + 256 * k] = d[k];
            __syncthreads();
        }
        // thread's 16 elems = 8 channels x 2 points: point A (hh=t0), B (hh=t0+2)
        const int w = tid & 127, t0 = tid >> 7;
        float vA[8], vB[8];
        #pragma unroll
        for (int cc = 0; cc < 8; ++cc) {
            vA[cc] = sU[cc * 512 + t0 * 128 + w];
            vB[cc] = sU[cc * 512 + (t0 + 2) * 128 + w];
        }
        __syncthreads();   // reads done before solve2 overwrites sU
        #pragma unroll
        for (int cc = 0; cc < 8; ++cc) {
            float aA = 0.f, aB = 0.f;
            #pragma unroll
            for (int j = 0; j < 8; ++j) {
                aA = fmaf(sM[cc * 8 + j], vA[j], aA);
                aB = fmaf(sM[cc * 8 + j], vB[j], aB);
            }
            d[2 * cc]     = aA;   // k even: (c=cc, hh=t0)
            d[2 * cc + 1] = aB;   // k odd : (c=cc, hh=t0+2)
        }
    }

    if (POST) jsolve_x(sU, tid, co, rb, d);     // same t -> same co/rb

    #pragma unroll
    for (int k = 0; k < 16; ++k) {
        const int p = tid + 256 * k;
        const int w = p & 127, hh = (p >> 7) & 3, c = p >> 9;
        udst[((size_t)(b * 8 + c) * S_ + (h0 + hh)) * S_ + w] = d[k];
    }
}

// ---------------------------------------------------------------------------
// y-phase solve along h. Block = (bc, 32-wide w tile), thread owns 16 elems
// p = tid + 256k with p = h*32 + wl.
// ---------------------------------------------------------------------------
__global__ __launch_bounds__(256) void ysweep_kernel(
    float* __restrict__ u,
    const float* __restrict__ bbeta, const float* __restrict__ btc, float t)
{
    __shared__ float sU[128 * 32];   // 16 KB

    const int tid = threadIdx.x;
    const int bc = blockIdx.x >> 2;
    const int c  = bc & 7;
    const int w0 = (blockIdx.x & 3) << 5;

    float d[16], co[16], rb[16], x[16];
    #pragma unroll
    for (int k = 0; k < 16; ++k) {
        const int p = tid + 256 * k;
        const int wl = p & 31, h = p >> 5;
        const size_t gi = ((size_t)bc * S_ + h) * S_ + w0 + wl;
        const int    ga = (c * S_ + h) * S_ + w0 + wl;
        d[k] = u[gi];
        float be = fmaf(btc[ga], t, bbeta[ga]);
        be = fminf(fmaxf(be, EPSF), 10.f);
        const float cc2 = be * 0.001f;          // * dt/dy^2
        co[k] = cc2;
        const float nb = (h == 0 || h == 127) ? 1.f : 2.f;
        rb[k] = __builtin_amdgcn_rcpf(fmaf(nb, cc2, 1.f) + EPSF);
    }

    #pragma unroll
    for (int k = 0; k < 16; ++k) { x[k] = rb[k] * d[k]; sU[tid + 256 * k] = x[k]; }
    __syncthreads();
    for (int it = 0; it < NIT; ++it) {
        #pragma unroll
        for (int k = 0; k < 16; ++k) {
            const int p = tid + 256 * k;
            const int h = p >> 5;
            const float xl = (h > 0)   ? sU[p - 32] : 0.f;
            const float xr = (h < 127) ? sU[p + 32] : 0.f;
            x[k] = rb[k] * fmaf(co[k], xl + xr, d[k]);
        }
        __syncthreads();
        #pragma unroll
        for (int k = 0; k < 16; ++k) sU[tid + 256 * k] = x[k];
        __syncthreads();
    }

    #pragma unroll
    for (int k = 0; k < 16; ++k) {
        const int p = tid + 256 * k;
        const int wl = p & 31, h = p >> 5;
        u[((size_t)bc * S_ + h) * S_ + w0 + wl] = x[k];
    }
}

extern "C" void kernel_launch(void* const* d_in, const int* in_sizes, int n_in,
                              void* d_out, int out_size, void* d_ws, size_t ws_size,
                              hipStream_t stream) {
    const float* u_in = (const float*)d_in[0];
    const float* ab   = (const float*)d_in[1];
    const float* bbta = (const float*)d_in[2];
    const float* atc  = (const float*)d_in[3];
    const float* btc  = (const float*)d_in[4];
    const float* cm   = (const float*)d_in[5];
    float* u = (float*)d_out;

    const dim3 xgrid(512), ygrid(512), blk(256);
    double t = 0.0;
    const double half = 0.0005;

    // step-0 head: mix + x half (t=0), reads pristine input, fills d_out
    xmix_kernel<false, true, true><<<xgrid, blk, 0, stream>>>(u_in, u, ab, atc, cm, (float)t);

    for (int k = 0; k < 10; ++k) {
        t += half;
        ysweep_kernel<<<ygrid, blk, 0, stream>>>(u, bbta, btc, (float)t);
        t += half;
        if (k < 9) {
            // trailing x of step k + mix + leading x of step k+1 (same t)
            xmix_kernel<true, true, true><<<xgrid, blk, 0, stream>>>(u, u, ab, atc, cm, (float)t);
        } else {
            xmix_kernel<true, false, false><<<xgrid, blk, 0, stream>>>(u, u, ab, atc, cm, (float)t);
        }
    }
}